// Round 2
// baseline (316.800 us; speedup 1.0000x reference)
//
#include <hip/hip_runtime.h>
#include <hip/hip_bf16.h>
#include <cstdint>
#include <cstddef>

typedef __bf16 bf16_t;
typedef bf16_t bf16x8 __attribute__((ext_vector_type(8)));
typedef bf16_t bf16x4 __attribute__((ext_vector_type(4)));
typedef float f32x4 __attribute__((ext_vector_type(4)));

#define BN_EPS 1e-5f

// ---- Prep: fold BN + bias into per-column scale/shift -----------------------
__global__ void prep_scales_kernel(const float* g1, const float* be1, const float* m1,
                                   const float* v1, const float* b1,
                                   const float* g2, const float* be2, const float* m2,
                                   const float* v2, const float* b2,
                                   float* s1, float* t1, float* s2, float* t2) {
  int i = blockIdx.x * 256 + threadIdx.x;
  if (i < 1024) {
    float s = g1[i] * rsqrtf(v1[i] + BN_EPS);
    s1[i] = s;
    t1[i] = be1[i] - m1[i] * s + b1[i] * s;  // bn(z+b1) = z*s + t
  }
  if (i < 512) {
    float s = g2[i] * rsqrtf(v2[i] + BN_EPS);
    s2[i] = s;
    t2[i] = be2[i] - m2[i] * s + b2[i] * s;
  }
}

// ---- Prep: W1 (257x1024 f32) -> W1T (1024x256 bf16, K-contig) + last row ----
__global__ void prep_w1t_kernel(const float* __restrict__ W1, bf16_t* __restrict__ W1T,
                                float* __restrict__ w1last) {
  int n = blockIdx.x;    // 0..1023
  int k = threadIdx.x;   // 0..255
  W1T[n * 256 + k] = (bf16_t)W1[k * 1024 + n];
  if (k == 0) w1last[n] = W1[256 * 1024 + n];  // conv-feature row, kept fp32
}

// ---- Prep: W2 (1024x512 f32) -> W2T (512x1024 bf16) -------------------------
__global__ void prep_w2t_kernel(const float* __restrict__ W2, bf16_t* __restrict__ W2T) {
  int n = blockIdx.x;    // 0..511
  int t = threadIdx.x;   // 0..255
#pragma unroll
  for (int i = 0; i < 4; ++i) {
    int k = i * 256 + t;
    W2T[n * 1024 + k] = (bf16_t)W2[k * 512 + n];
  }
}

// ---- Fully fused MLP: x -> h1 (LDS only) -> h2 (regs) -> sigmoid(out) -------
// Block: 64 rows, 256 threads (4 waves).
// GEMM1: wave w computes 64 rows x 32 cols of each 128-col chunk.
// GEMM2: wave w computes 64 rows x cols [w*128, w*128+128), acc2 = 32 f32x4.
// LDS strides padded (264 / 136 elems) to rotate banks across rows.
__global__ __launch_bounds__(256, 2) void fused_mlp_kernel(
    const float* __restrict__ x,
    const bf16_t* __restrict__ W1T,      // [1024][256]
    const bf16_t* __restrict__ W2T,      // [512][1024]
    const float* __restrict__ s1, const float* __restrict__ t1,
    const float* __restrict__ w1last,
    const float* __restrict__ s2, const float* __restrict__ t2,
    const float* __restrict__ W3, const float* __restrict__ b3,
    float* __restrict__ out) {
  __shared__ __align__(16) bf16_t xs[64 * 264];
  __shared__ __align__(16) bf16_t h1s[64 * 136];
  __shared__ float convs[64];
  __shared__ float rowsum[64 * 4];

  const int tid = threadIdx.x;
  const int lane = tid & 63;
  const int w = tid >> 6;
  const int l15 = lane & 15;
  const int quad = lane >> 4;
  const int row0 = blockIdx.x * 64;

  // ---- Stage x (fp32 -> bf16) into LDS + per-row conv feature ----
#pragma unroll
  for (int it = 0; it < 16; ++it) {
    int r = it * 4 + w;
    const float4 v = *(const float4*)(x + (size_t)(row0 + r) * 256 + lane * 4);
    float s = v.x + v.y + v.z + v.w;
    bf16x4 o = {(bf16_t)v.x, (bf16_t)v.y, (bf16_t)v.z, (bf16_t)v.w};
    *(bf16x4*)(xs + r * 264 + lane * 4) = o;
#pragma unroll
    for (int off = 32; off >= 1; off >>= 1) s += __shfl_down(s, off);
    if (lane == 0) convs[r] = (s > 0.0f) ? 1.0f : 0.0f;  // mean>0 <=> sum>0
  }
  __syncthreads();

  f32x4 acc2[4][8];
#pragma unroll
  for (int i = 0; i < 4; ++i)
#pragma unroll
    for (int j = 0; j < 8; ++j) {
      f32x4 z = {0.f, 0.f, 0.f, 0.f};
      acc2[i][j] = z;
    }

  for (int kc = 0; kc < 8; ++kc) {
    // ---- GEMM1 chunk: 64 rows x 32 cols (this wave), K=256 ----
    const int colbase = kc * 128 + w * 32;
    const bf16_t* Wb = W1T + (size_t)colbase * 256;
    f32x4 acc1[4][2];
#pragma unroll
    for (int i = 0; i < 4; ++i)
#pragma unroll
      for (int j = 0; j < 2; ++j) {
        f32x4 z = {0.f, 0.f, 0.f, 0.f};
        acc1[i][j] = z;
      }
#pragma unroll
    for (int ks = 0; ks < 8; ++ks) {
      bf16x8 af[4];
#pragma unroll
      for (int ti = 0; ti < 4; ++ti)
        af[ti] = *(const bf16x8*)(xs + (ti * 16 + l15) * 264 + ks * 32 + quad * 8);
#pragma unroll
      for (int tj = 0; tj < 2; ++tj) {
        bf16x8 bfr = *(const bf16x8*)(Wb + (size_t)(tj * 16 + l15) * 256 + ks * 32 + quad * 8);
#pragma unroll
        for (int ti = 0; ti < 4; ++ti)
          acc1[ti][tj] = __builtin_amdgcn_mfma_f32_16x16x32_bf16(af[ti], bfr, acc1[ti][tj], 0, 0, 0);
      }
    }
    // guard: previous chunk's GEMM2 reads of h1s must complete before overwrite
    __syncthreads();
    // ---- epilogue: conv rank-1 + BN1 + ReLU -> h1s (bf16) ----
    float s1c[2], t1c[2], wlc[2];
#pragma unroll
    for (int tj = 0; tj < 2; ++tj) {
      int c = colbase + tj * 16 + l15;
      s1c[tj] = s1[c];
      t1c[tj] = t1[c];
      wlc[tj] = w1last[c];
    }
#pragma unroll
    for (int ti = 0; ti < 4; ++ti)
#pragma unroll
      for (int r = 0; r < 4; ++r) {
        int rr = ti * 16 + quad * 4 + r;
        float cf = convs[rr];
#pragma unroll
        for (int tj = 0; tj < 2; ++tj) {
          float z = acc1[ti][tj][r] + cf * wlc[tj];
          z = fmaxf(z * s1c[tj] + t1c[tj], 0.f);
          h1s[rr * 136 + w * 32 + tj * 16 + l15] = (bf16_t)z;
        }
      }
    __syncthreads();
    // ---- GEMM2 accumulate: acc2 += h1s(64x128) @ W2T[w*128..+128][kc*128..+128]^T
    const bf16_t* W2b = W2T + (size_t)(w * 128) * 1024 + kc * 128;
#pragma unroll
    for (int k2 = 0; k2 < 4; ++k2) {
      bf16x8 af2[4];
#pragma unroll
      for (int ti = 0; ti < 4; ++ti)
        af2[ti] = *(const bf16x8*)(h1s + (ti * 16 + l15) * 136 + k2 * 32 + quad * 8);
#pragma unroll
      for (int tj = 0; tj < 8; ++tj) {
        bf16x8 bfr = *(const bf16x8*)(W2b + (size_t)(tj * 16 + l15) * 1024 + k2 * 32 + quad * 8);
#pragma unroll
        for (int ti = 0; ti < 4; ++ti)
          acc2[ti][tj] = __builtin_amdgcn_mfma_f32_16x16x32_bf16(af2[ti], bfr, acc2[ti][tj], 0, 0, 0);
      }
    }
  }

  // ---- Final: BN2 + ReLU + dot(W3) + sigmoid ----
  float s2c[8], t2c[8], w3c[8];
#pragma unroll
  for (int tj = 0; tj < 8; ++tj) {
    int c = w * 128 + tj * 16 + l15;
    s2c[tj] = s2[c];
    t2c[tj] = t2[c];
    w3c[tj] = W3[c];
  }
  float part[4][4];
#pragma unroll
  for (int ti = 0; ti < 4; ++ti)
#pragma unroll
    for (int r = 0; r < 4; ++r) {
      float p = 0.f;
#pragma unroll
      for (int tj = 0; tj < 8; ++tj) {
        float z = fmaxf(acc2[ti][tj][r] * s2c[tj] + t2c[tj], 0.f);
        p += z * w3c[tj];
      }
      part[ti][r] = p;
    }
  // reduce across the 16 l15 lanes (masks 1..8 stay within the group)
#pragma unroll
  for (int m = 1; m <= 8; m <<= 1)
#pragma unroll
    for (int ti = 0; ti < 4; ++ti)
#pragma unroll
      for (int r = 0; r < 4; ++r) part[ti][r] += __shfl_xor(part[ti][r], m);
  if (l15 == 0) {
#pragma unroll
    for (int ti = 0; ti < 4; ++ti)
#pragma unroll
      for (int r = 0; r < 4; ++r) rowsum[(ti * 16 + quad * 4 + r) * 4 + w] = part[ti][r];
  }
  __syncthreads();
  if (tid < 64) {
    float z = rowsum[tid * 4] + rowsum[tid * 4 + 1] + rowsum[tid * 4 + 2] + rowsum[tid * 4 + 3] + b3[0];
    out[row0 + tid] = 1.0f / (1.0f + expf(-z));
  }
}

extern "C" void kernel_launch(void* const* d_in, const int* in_sizes, int n_in,
                              void* d_out, int out_size, void* d_ws, size_t ws_size,
                              hipStream_t stream) {
  const float* x = (const float*)d_in[0];
  const float* W1 = (const float*)d_in[1];
  const float* b1 = (const float*)d_in[2];
  const float* g1 = (const float*)d_in[3];
  const float* be1 = (const float*)d_in[4];
  const float* m1 = (const float*)d_in[5];
  const float* v1 = (const float*)d_in[6];
  const float* W2 = (const float*)d_in[7];
  const float* b2 = (const float*)d_in[8];
  const float* g2 = (const float*)d_in[9];
  const float* be2 = (const float*)d_in[10];
  const float* m2 = (const float*)d_in[11];
  const float* v2 = (const float*)d_in[12];
  const float* W3 = (const float*)d_in[13];
  const float* b3 = (const float*)d_in[14];
  float* out = (float*)d_out;

  char* p = (char*)d_ws;
  bf16_t* W1T = (bf16_t*)p;   p += (size_t)1024 * 256 * 2;
  bf16_t* W2T = (bf16_t*)p;   p += (size_t)512 * 1024 * 2;
  float* w1last = (float*)p;  p += 1024 * 4;
  float* s1 = (float*)p;      p += 1024 * 4;
  float* t1 = (float*)p;      p += 1024 * 4;
  float* s2 = (float*)p;      p += 512 * 4;
  float* t2 = (float*)p;      p += 512 * 4;

  prep_scales_kernel<<<4, 256, 0, stream>>>(g1, be1, m1, v1, b1, g2, be2, m2, v2, b2, s1, t1, s2, t2);
  prep_w1t_kernel<<<1024, 256, 0, stream>>>(W1, W1T, w1last);
  prep_w2t_kernel<<<512, 256, 0, stream>>>(W2, W2T);

  fused_mlp_kernel<<<1024, 256, 0, stream>>>(x, W1T, W2T, s1, t1, w1last, s2, t2, W3, b3, out);
}